// Round 1
// baseline (10882.557 us; speedup 1.0000x reference)
//
#include <hip/hip_runtime.h>

// LSTM B=64 T=2048 D=H=256.
// Kernel 1 (lstm_proj): xg[t][j][b] = sum_d x[b,t,d]*Wi[d,j] + bias[j], fp16 out, MFMA f16.
// Kernel 2 (lstm_recur): persistent scan, 4 blocks x 16 batch rows, W_h fp16 resident
//   (6/8 col-tiles per wave in VGPR B-fragments, 2/8 in LDS), fp32 cell state in LDS.
// MFMA 16x16x32 f16 layouts (guide §3, m89/m91/m120):
//   A[m = lane&15][k = (lane>>4)*8 + j], B[k = (lane>>4)*8 + j][n = lane&15],
//   C row = (lane>>4)*4 + reg, col = lane&15.

#define T_ALL 2048
#define NBATCH 64
#define HD 256
#define NG 1024
#define HS_N ((size_t)NBATCH * T_ALL * HD)

typedef _Float16 h8 __attribute__((ext_vector_type(8)));
typedef _Float16 h4 __attribute__((ext_vector_type(4)));
typedef float f4 __attribute__((ext_vector_type(4)));

#define SMEM_W 131072              // 16 LDS weight tiles x 8KB
#define SMEM_H 8448                // h: 16 rows x 264 fp16 (pad 8 to break 512B stride)
#define SMEM_C 16384               // c: 16 rows x 256 fp32
#define SMEM_TOTAL (SMEM_W + SMEM_H + SMEM_C)   // 155904 <= 163840

__device__ __forceinline__ float sigf(float x) {
  return __builtin_amdgcn_rcpf(1.f + __expf(-x));
}
__device__ __forceinline__ float tanh_f(float x) {
  return 2.f * __builtin_amdgcn_rcpf(1.f + __expf(-2.f * x)) - 1.f;
}

// ---------------- input projection: one block per timestep ----------------
__global__ __launch_bounds__(256, 2) void lstm_proj(
    const float* __restrict__ x, const float* __restrict__ Wi,
    const float* __restrict__ bias, _Float16* __restrict__ xg, int t0)
{
  const int t = t0 + blockIdx.x;
  const int tid = threadIdx.x;
  const int w = tid >> 6, L = tid & 63;
  const int n = L & 15, quad = L >> 4;

  // B-fragments: x^T[k][b] — reused across all j tiles. 32 frags = 128 VGPRs.
  h8 bx[8][4];
#pragma unroll
  for (int kt = 0; kt < 8; ++kt) {
#pragma unroll
    for (int bt = 0; bt < 4; ++bt) {
      const int b = bt * 16 + n, k = kt * 32 + quad * 8;
      const float* p = x + ((size_t)b * T_ALL + t) * HD + k;
      f4 lo = *(const f4*)p, hi = *(const f4*)(p + 4);
      h8 f;
      f[0] = (_Float16)lo[0]; f[1] = (_Float16)lo[1];
      f[2] = (_Float16)lo[2]; f[3] = (_Float16)lo[3];
      f[4] = (_Float16)hi[0]; f[5] = (_Float16)hi[1];
      f[6] = (_Float16)hi[2]; f[7] = (_Float16)hi[3];
      bx[kt][bt] = f;
    }
  }

  for (int i = 0; i < 16; ++i) {       // wave w owns j-tiles w*16 .. w*16+15
    const int jt = w * 16 + i;
    float bv0 = bias[jt * 16 + quad * 4 + 0];
    float bv1 = bias[jt * 16 + quad * 4 + 1];
    float bv2 = bias[jt * 16 + quad * 4 + 2];
    float bv3 = bias[jt * 16 + quad * 4 + 3];
    f4 acc[4];
#pragma unroll
    for (int bt = 0; bt < 4; ++bt) {
      acc[bt][0] = bv0; acc[bt][1] = bv1; acc[bt][2] = bv2; acc[bt][3] = bv3;
    }
#pragma unroll
    for (int kt = 0; kt < 8; ++kt) {
      const int j = jt * 16 + n, kb = kt * 32 + quad * 8;
      h8 a;   // A = Wi^T: A[m=j][k=d] = Wi[d][j]
#pragma unroll
      for (int jj = 0; jj < 8; ++jj) a[jj] = (_Float16)Wi[(size_t)(kb + jj) * NG + j];
#pragma unroll
      for (int bt = 0; bt < 4; ++bt)
        acc[bt] = __builtin_amdgcn_mfma_f32_16x16x32_f16(a, bx[kt][bt], acc[bt], 0, 0, 0);
    }
#pragma unroll
    for (int bt = 0; bt < 4; ++bt) {
#pragma unroll
      for (int r = 0; r < 4; ++r) {
        const int j = jt * 16 + quad * 4 + r, b = bt * 16 + n;
        xg[((size_t)blockIdx.x * NG + j) * 64 + b] = (_Float16)acc[bt][r];
      }
    }
  }
}

// ---------------- persistent recurrence: 4 blocks x 16 batch rows ----------------
__global__ __launch_bounds__(512, 2) void lstm_recur(
    const _Float16* __restrict__ xg, const float* __restrict__ Wh,
    float* __restrict__ out, _Float16* __restrict__ ws_h, float* __restrict__ ws_c,
    int t0, int CT)
{
  extern __shared__ char smem[];
  _Float16* w_lds = (_Float16*)smem;                     // [16 tiles][8 kt][64 lanes][8]
  _Float16* h_lds = (_Float16*)(smem + SMEM_W);          // [16][264]
  float*    c_lds = (float*)(smem + SMEM_W + SMEM_H);    // [16][256]

  const int tid = threadIdx.x;
  const int w = tid >> 6, L = tid & 63;
  const int n = L & 15, quad = L >> 4;
  const int b_base = blockIdx.x * 16;

  // Wave w owns col-tile quadruples q in {2w, 2w+1}; tile ct=(gate g=ct>>1, qi=ct&1),
  // gate-col base j0 = g*256 + (2w + qi)*16. ct 0..5 in VGPRs, ct 6..7 (o-gate) in LDS.
  h8 breg[6][8];
#pragma unroll
  for (int ct = 0; ct < 8; ++ct) {
    const int g = ct >> 1, q = 2 * w + (ct & 1);
    const int j = g * 256 + q * 16 + n;
#pragma unroll
    for (int kt = 0; kt < 8; ++kt) {
      const int kb = kt * 32 + quad * 8;
      h8 f;
#pragma unroll
      for (int jj = 0; jj < 8; ++jj) f[jj] = (_Float16)Wh[(size_t)(kb + jj) * NG + j];
      if (ct < 6) breg[ct][kt] = f;
      else *(h8*)(w_lds + (((w * 2 + (ct - 6)) * 8 + kt) * 64 + L) * 8) = f;
    }
  }

  if (t0 == 0) {
    for (int i = tid; i < 16 * 264; i += 512) h_lds[i] = (_Float16)0.f;
    for (int i = tid; i < 16 * 256; i += 512) c_lds[i] = 0.f;
  } else {
    const int idx = tid * 8, r = idx >> 8, c = idx & 255;
    *(h8*)(h_lds + r * 264 + c) = *(const h8*)(ws_h + (size_t)(b_base + r) * HD + c);
    *(f4*)(c_lds + r * 256 + c)     = *(const f4*)(ws_c + (size_t)(b_base + r) * HD + c);
    *(f4*)(c_lds + r * 256 + c + 4) = *(const f4*)(ws_c + (size_t)(b_base + r) * HD + c + 4);
  }
  __syncthreads();

  int voffg[4];   // xg element offset per gate (lane's column j, its 4 batch rows)
#pragma unroll
  for (int g = 0; g < 4; ++g)
    voffg[g] = (g * 256 + 2 * w * 16 + n) * 64 + b_base + quad * 4;

  const int a_off = n * 264 + quad * 8;   // A-frag: h_lds[m = lane&15][k = quad*8 + kt*32]

#pragma unroll 1
  for (int tt = 0; tt < CT; ++tt) {
    const int t = t0 + tt;
    const _Float16* xb = xg + (size_t)tt * (NG * 64);
    h4 xq[8];
#pragma unroll
    for (int ct = 0; ct < 8; ++ct)
      xq[ct] = *(const h4*)(xb + voffg[ct >> 1] + (ct & 1) * 1024);

    f4 acc[8];
#pragma unroll
    for (int ct = 0; ct < 8; ++ct) { acc[ct][0] = 0.f; acc[ct][1] = 0.f; acc[ct][2] = 0.f; acc[ct][3] = 0.f; }

#pragma unroll
    for (int kt = 0; kt < 8; ++kt) {
      h8 a = *(const h8*)(h_lds + a_off + kt * 32);
#pragma unroll
      for (int ct = 0; ct < 6; ++ct)
        acc[ct] = __builtin_amdgcn_mfma_f32_16x16x32_f16(a, breg[ct][kt], acc[ct], 0, 0, 0);
#pragma unroll
      for (int ct = 6; ct < 8; ++ct) {
        h8 bl = *(const h8*)(w_lds + (((w * 2 + (ct - 6)) * 8 + kt) * 64 + L) * 8);
        acc[ct] = __builtin_amdgcn_mfma_f32_16x16x32_f16(a, bl, acc[ct], 0, 0, 0);
      }
    }
    __syncthreads();   // all h_lds reads done before epilogue overwrites

#pragma unroll
    for (int qi = 0; qi < 2; ++qi) {
      const int c_col = (2 * w + qi) * 16 + n;
#pragma unroll
      for (int r = 0; r < 4; ++r) {
        const int row = quad * 4 + r;
        const float vi = acc[0 + qi][r] + (float)xq[0 + qi][r];
        const float vf = acc[2 + qi][r] + (float)xq[2 + qi][r];
        const float vg = acc[4 + qi][r] + (float)xq[4 + qi][r];
        const float vo = acc[6 + qi][r] + (float)xq[6 + qi][r];
        const float cprev = c_lds[row * 256 + c_col];
        const float cn = sigf(vf) * cprev + sigf(vi) * tanh_f(vg);
        const float hn = sigf(vo) * tanh_f(cn);
        c_lds[row * 256 + c_col] = cn;
        h_lds[row * 264 + c_col] = (_Float16)hn;
        out[((size_t)(b_base + row) * T_ALL + t) * HD + c_col] = hn;
        if (t == T_ALL - 1) {
          out[HS_N + (size_t)(b_base + row) * HD + c_col] = hn;                         // h_T
          out[HS_N + (size_t)NBATCH * HD + (size_t)(b_base + row) * HD + c_col] = cn;   // c_T
        }
      }
    }
    __syncthreads();   // epilogue writes done before next step reads h_lds
  }

  { // persist state for next chunk
    const int idx = tid * 8, r = idx >> 8, c = idx & 255;
    *(h8*)(ws_h + (size_t)(b_base + r) * HD + c) = *(const h8*)(h_lds + r * 264 + c);
    *(f4*)(ws_c + (size_t)(b_base + r) * HD + c)     = *(const f4*)(c_lds + r * 256 + c);
    *(f4*)(ws_c + (size_t)(b_base + r) * HD + c + 4) = *(const f4*)(c_lds + r * 256 + c + 4);
  }
}

extern "C" void kernel_launch(void* const* d_in, const int* in_sizes, int n_in,
                              void* d_out, int out_size, void* d_ws, size_t ws_size,
                              hipStream_t stream) {
  (void)in_sizes; (void)n_in; (void)out_size;
  const float* x    = (const float*)d_in[0];
  const float* Wi   = (const float*)d_in[1];
  const float* Wh   = (const float*)d_in[2];
  const float* bias = (const float*)d_in[3];
  float* out = (float*)d_out;

  // ws: xg chunk [CT][1024][64] fp16, then h state [64][256] fp16, c state [64][256] fp32
  const size_t state_bytes = (size_t)NBATCH * HD * 2 + (size_t)NBATCH * HD * 4;
  int CT = T_ALL;
  while (CT > 32 && (size_t)CT * NG * 64 * 2 + state_bytes > ws_size) CT >>= 1;

  _Float16* xg   = (_Float16*)d_ws;
  _Float16* ws_h = (_Float16*)((char*)d_ws + (size_t)CT * NG * 64 * 2);
  float*    ws_c = (float*)((char*)ws_h + (size_t)NBATCH * HD * 2);

  (void)hipFuncSetAttribute((const void*)lstm_recur,
                            hipFuncAttributeMaxDynamicSharedMemorySize, SMEM_TOTAL);

  for (int t0 = 0; t0 < T_ALL; t0 += CT) {
    lstm_proj<<<dim3(CT), dim3(256), 0, stream>>>(x, Wi, bias, xg, t0);
    lstm_recur<<<dim3(4), dim3(512), SMEM_TOTAL, stream>>>(xg, Wh, out, ws_h, ws_c, t0, CT);
  }
}

// Round 2
// 8091.997 us; speedup vs baseline: 1.3449x; 1.3449x over previous
//
#include <hip/hip_runtime.h>

// LSTM B=64 T=2048 D=H=256.
// lstm_proj: xg[t][bg][j][16b] = x@W_i + bias (fp16, MFMA f16), block-contiguous layout.
// lstm_recur: persistent scan, 4 blocks x 16 batch rows. Weight residency per block (CU):
//   gate i (cols   0..255): fp8 e4m3 in VGPRs (2 tiles/wave, 16 regs/tile-row)
//   gate f (cols 256..511): fp16 in VGPRs (2 tiles/wave)
//   gate g (cols 512..767): fp16 in LDS (16 tiles, 128 KB)
//   gate o (cols 768..1023): fp8 e4m3 in VGPRs
// c-state is lane-private -> 8 VGPRs. h round-trips through LDS in fp16 AND fp8.
// MFMA 16x16x32 (f16 and fp8_fp8, both 8 elem/lane):
//   A[m=lane&15][k=(lane>>4)*8+j], B[k=(lane>>4)*8+j][n=lane&15],
//   C row=(lane>>4)*4+reg, col=lane&15.

#define T_ALL 2048
#define NBATCH 64
#define HD 256
#define NG 1024
#define HS_N ((size_t)NBATCH * T_ALL * HD)

typedef _Float16 h8 __attribute__((ext_vector_type(8)));
typedef _Float16 h4 __attribute__((ext_vector_type(4)));
typedef float f4 __attribute__((ext_vector_type(4)));

#define SMEM_W 131072                 // g-gate: 16 tiles x [8kt][64 lanes][8 halfs]
#define SMEM_H 8448                   // h fp16: 16 rows x 264 (pad: 528B = 33 x 16B)
#define SMEM_H8 4224                  // h fp8:  16 rows x 264 bytes (264 = 8*33)
#define SMEM_TOTAL (SMEM_W + SMEM_H + SMEM_H8)   // 143744 <= 163840

__device__ __forceinline__ float sigf(float x) {
  return __builtin_amdgcn_rcpf(1.f + __expf(-x));
}
__device__ __forceinline__ float tanh_f(float x) {
  return 2.f * __builtin_amdgcn_rcpf(1.f + __expf(-2.f * x)) - 1.f;
}
__device__ __forceinline__ unsigned char to_fp8(float x) {
  return (unsigned char)(__builtin_amdgcn_cvt_pk_fp8_f32(x, x, 0, false) & 0xFF);
}

// ---------------- input projection: one block per timestep ----------------
__global__ __launch_bounds__(256, 2) void lstm_proj(
    const float* __restrict__ x, const float* __restrict__ Wi,
    const float* __restrict__ bias, _Float16* __restrict__ xg, int t0)
{
  const int t = t0 + blockIdx.x;
  const int tid = threadIdx.x;
  const int w = tid >> 6, L = tid & 63;
  const int n = L & 15, quad = L >> 4;

  // B-fragments: x^T[k][b], reused across all j tiles (32 frags = 128 VGPRs)
  h8 bx[8][4];
#pragma unroll
  for (int kt = 0; kt < 8; ++kt) {
#pragma unroll
    for (int bt = 0; bt < 4; ++bt) {
      const int b = bt * 16 + n, k = kt * 32 + quad * 8;
      const float* p = x + ((size_t)b * T_ALL + t) * HD + k;
      f4 lo = *(const f4*)p, hi = *(const f4*)(p + 4);
      h8 f;
      f[0] = (_Float16)lo[0]; f[1] = (_Float16)lo[1];
      f[2] = (_Float16)lo[2]; f[3] = (_Float16)lo[3];
      f[4] = (_Float16)hi[0]; f[5] = (_Float16)hi[1];
      f[6] = (_Float16)hi[2]; f[7] = (_Float16)hi[3];
      bx[kt][bt] = f;
    }
  }

  for (int i = 0; i < 16; ++i) {       // wave w owns j-tiles w*16 .. w*16+15
    const int jt = w * 16 + i;
    float bv0 = bias[jt * 16 + quad * 4 + 0];
    float bv1 = bias[jt * 16 + quad * 4 + 1];
    float bv2 = bias[jt * 16 + quad * 4 + 2];
    float bv3 = bias[jt * 16 + quad * 4 + 3];
    f4 acc[4];
#pragma unroll
    for (int bt = 0; bt < 4; ++bt) {
      acc[bt][0] = bv0; acc[bt][1] = bv1; acc[bt][2] = bv2; acc[bt][3] = bv3;
    }
#pragma unroll
    for (int kt = 0; kt < 8; ++kt) {
      const int j = jt * 16 + n, kb = kt * 32 + quad * 8;
      h8 a;   // A = Wi^T: A[m=j][k=d] = Wi[d][j]
#pragma unroll
      for (int jj = 0; jj < 8; ++jj) a[jj] = (_Float16)Wi[(size_t)(kb + jj) * NG + j];
#pragma unroll
      for (int bt = 0; bt < 4; ++bt)
        acc[bt] = __builtin_amdgcn_mfma_f32_16x16x32_f16(a, bx[kt][bt], acc[bt], 0, 0, 0);
    }
#pragma unroll
    for (int bt = 0; bt < 4; ++bt) {
#pragma unroll
      for (int r = 0; r < 4; ++r) {
        const int j = jt * 16 + quad * 4 + r;   // gate col
        xg[(((size_t)blockIdx.x * 4 + bt) * NG + j) * 16 + n] = (_Float16)acc[bt][r];
      }
    }
  }
}

// ---------------- persistent recurrence: 4 blocks x 16 batch rows ----------------
__global__ __launch_bounds__(512, 2) void lstm_recur(
    const _Float16* __restrict__ xg, const float* __restrict__ Wh,
    float* __restrict__ out, _Float16* __restrict__ ws_h, float* __restrict__ ws_c,
    int t0, int CT)
{
  extern __shared__ char smem[];
  _Float16* w_lds = (_Float16*)smem;                              // g-gate tiles
  _Float16* h_lds = (_Float16*)(smem + SMEM_W);                   // [16][264] fp16
  unsigned char* h8_lds = (unsigned char*)(smem + SMEM_W + SMEM_H); // [16][264] fp8

  const int tid = threadIdx.x;
  const int w = tid >> 6, L = tid & 63;
  const int n = L & 15, quad = L >> 4;
  const int b_base = blockIdx.x * 16;

  // ---- load resident weights (one-time) ----
  h8  bF[2][8];                    // f gate fp16: 64 VGPRs
  long bI[2][8], bO[2][8];         // i / o gates fp8 packed: 32 + 32 VGPRs
#pragma unroll
  for (int qi = 0; qi < 2; ++qi) {
    const int q = 2 * w + qi;
    for (int kt = 0; kt < 8; ++kt) {
      const int kb = kt * 32 + quad * 8;
      { // f gate, fp16 regs
        const int j = 256 + q * 16 + n;
        h8 f;
#pragma unroll
        for (int jj = 0; jj < 8; ++jj) f[jj] = (_Float16)Wh[(size_t)(kb + jj) * NG + j];
        bF[qi][kt] = f;
      }
      { // i gate, fp8 regs
        const int j = 0 + q * 16 + n;
        unsigned lo = 0, hi = 0;
        lo = __builtin_amdgcn_cvt_pk_fp8_f32(Wh[(size_t)(kb + 0) * NG + j], Wh[(size_t)(kb + 1) * NG + j], lo, false);
        lo = __builtin_amdgcn_cvt_pk_fp8_f32(Wh[(size_t)(kb + 2) * NG + j], Wh[(size_t)(kb + 3) * NG + j], lo, true);
        hi = __builtin_amdgcn_cvt_pk_fp8_f32(Wh[(size_t)(kb + 4) * NG + j], Wh[(size_t)(kb + 5) * NG + j], hi, false);
        hi = __builtin_amdgcn_cvt_pk_fp8_f32(Wh[(size_t)(kb + 6) * NG + j], Wh[(size_t)(kb + 7) * NG + j], hi, true);
        bI[qi][kt] = (long)(((unsigned long)hi << 32) | (unsigned long)lo);
      }
      { // o gate, fp8 regs
        const int j = 768 + q * 16 + n;
        unsigned lo = 0, hi = 0;
        lo = __builtin_amdgcn_cvt_pk_fp8_f32(Wh[(size_t)(kb + 0) * NG + j], Wh[(size_t)(kb + 1) * NG + j], lo, false);
        lo = __builtin_amdgcn_cvt_pk_fp8_f32(Wh[(size_t)(kb + 2) * NG + j], Wh[(size_t)(kb + 3) * NG + j], lo, true);
        hi = __builtin_amdgcn_cvt_pk_fp8_f32(Wh[(size_t)(kb + 4) * NG + j], Wh[(size_t)(kb + 5) * NG + j], hi, false);
        hi = __builtin_amdgcn_cvt_pk_fp8_f32(Wh[(size_t)(kb + 6) * NG + j], Wh[(size_t)(kb + 7) * NG + j], hi, true);
        bO[qi][kt] = (long)(((unsigned long)hi << 32) | (unsigned long)lo);
      }
      { // g gate -> LDS
        const int j = 512 + q * 16 + n;
        h8 f;
#pragma unroll
        for (int jj = 0; jj < 8; ++jj) f[jj] = (_Float16)Wh[(size_t)(kb + jj) * NG + j];
        *(h8*)(w_lds + ((size_t)(q * 8 + kt) * 64 + L) * 8) = f;
      }
    }
  }

  // ---- state init / restore ----
  float creg[8];                    // lane-private c: row=quad*4+r, col=(2w+qi)*16+n
  if (t0 == 0) {
    for (int i = tid; i < 16 * 264; i += 512) h_lds[i] = (_Float16)0.f;
    for (int i = tid * 4; i < 16 * 264; i += 512 * 4) *(unsigned*)(h8_lds + i) = 0u;
#pragma unroll
    for (int i = 0; i < 8; ++i) creg[i] = 0.f;
  } else {
    const int idx = tid * 8, r = idx >> 8, c = idx & 255;
    h8 hv = *(const h8*)(ws_h + (size_t)(b_base + r) * HD + c);
    *(h8*)(h_lds + r * 264 + c) = hv;
    unsigned lo = 0, hi = 0;
    lo = __builtin_amdgcn_cvt_pk_fp8_f32((float)hv[0], (float)hv[1], lo, false);
    lo = __builtin_amdgcn_cvt_pk_fp8_f32((float)hv[2], (float)hv[3], lo, true);
    hi = __builtin_amdgcn_cvt_pk_fp8_f32((float)hv[4], (float)hv[5], hi, false);
    hi = __builtin_amdgcn_cvt_pk_fp8_f32((float)hv[6], (float)hv[7], hi, true);
    *(unsigned*)(h8_lds + r * 264 + c) = lo;
    *(unsigned*)(h8_lds + r * 264 + c + 4) = hi;
#pragma unroll
    for (int qi = 0; qi < 2; ++qi)
#pragma unroll
      for (int r2 = 0; r2 < 4; ++r2)
        creg[qi * 4 + r2] = ws_c[(size_t)(b_base + quad * 4 + r2) * HD + (2 * w + qi) * 16 + n];
  }
  __syncthreads();

  // ---- precomputed addressing ----
  const int a16_off = n * 264 + quad * 8;           // h_lds (halfs)
  const int a8_off  = n * 264 + quad * 8;           // h8_lds (bytes)
  int loff[8];                                       // xq: ct = gate*2+qi
#pragma unroll
  for (int ct = 0; ct < 8; ++ct) {
    const int g = ct >> 1, qi = ct & 1;
    loff[ct] = ((g * 256 + (2 * w + qi) * 16 + n) << 4) + quad * 4;
  }
  const _Float16* xgp = xg + (size_t)blockIdx.x * (NG * 16);
  float* po[4];
#pragma unroll
  for (int r = 0; r < 4; ++r)
    po[r] = out + ((size_t)(b_base + quad * 4 + r) * T_ALL + t0) * HD + 2 * w * 16 + n;

#pragma unroll 1
  for (int tt = 0; tt < CT; ++tt) {
    const int t = t0 + tt;
    h4 xq[8];
#pragma unroll
    for (int ct = 0; ct < 8; ++ct) xq[ct] = *(const h4*)(xgp + loff[ct]);

    f4 aI[2], aF[2], aG[2], aO[2];
#pragma unroll
    for (int qi = 0; qi < 2; ++qi) {
      aI[qi][0]=0.f; aI[qi][1]=0.f; aI[qi][2]=0.f; aI[qi][3]=0.f;
      aF[qi][0]=0.f; aF[qi][1]=0.f; aF[qi][2]=0.f; aF[qi][3]=0.f;
      aG[qi][0]=0.f; aG[qi][1]=0.f; aG[qi][2]=0.f; aG[qi][3]=0.f;
      aO[qi][0]=0.f; aO[qi][1]=0.f; aO[qi][2]=0.f; aO[qi][3]=0.f;
    }

#pragma unroll
    for (int kt = 0; kt < 8; ++kt) {
      h8  a16 = *(const h8*)(h_lds + a16_off + kt * 32);
      long a8 = *(const long*)(h8_lds + a8_off + kt * 32);
      h8 bg0 = *(const h8*)(w_lds + ((size_t)((2 * w + 0) * 8 + kt) * 64 + L) * 8);
      h8 bg1 = *(const h8*)(w_lds + ((size_t)((2 * w + 1) * 8 + kt) * 64 + L) * 8);
      aF[0] = __builtin_amdgcn_mfma_f32_16x16x32_f16(a16, bF[0][kt], aF[0], 0, 0, 0);
      aF[1] = __builtin_amdgcn_mfma_f32_16x16x32_f16(a16, bF[1][kt], aF[1], 0, 0, 0);
      aG[0] = __builtin_amdgcn_mfma_f32_16x16x32_f16(a16, bg0, aG[0], 0, 0, 0);
      aG[1] = __builtin_amdgcn_mfma_f32_16x16x32_f16(a16, bg1, aG[1], 0, 0, 0);
      aI[0] = __builtin_amdgcn_mfma_f32_16x16x32_fp8_fp8(a8, bI[0][kt], aI[0], 0, 0, 0);
      aI[1] = __builtin_amdgcn_mfma_f32_16x16x32_fp8_fp8(a8, bI[1][kt], aI[1], 0, 0, 0);
      aO[0] = __builtin_amdgcn_mfma_f32_16x16x32_fp8_fp8(a8, bO[0][kt], aO[0], 0, 0, 0);
      aO[1] = __builtin_amdgcn_mfma_f32_16x16x32_fp8_fp8(a8, bO[1][kt], aO[1], 0, 0, 0);
    }
    __syncthreads();   // all h/w LDS reads complete before epilogue overwrites h

#pragma unroll
    for (int qi = 0; qi < 2; ++qi) {
      const int c_col = (2 * w + qi) * 16 + n;
#pragma unroll
      for (int r = 0; r < 4; ++r) {
        const int row = quad * 4 + r;
        const float vi = aI[qi][r] + (float)xq[0 + qi][r];
        const float vf = aF[qi][r] + (float)xq[2 + qi][r];
        const float vg = aG[qi][r] + (float)xq[4 + qi][r];
        const float vo = aO[qi][r] + (float)xq[6 + qi][r];
        const float cn = sigf(vf) * creg[qi * 4 + r] + sigf(vi) * tanh_f(vg);
        const float hn = sigf(vo) * tanh_f(cn);
        creg[qi * 4 + r] = cn;
        h_lds[row * 264 + c_col] = (_Float16)hn;
        h8_lds[row * 264 + c_col] = to_fp8(hn);
        po[r][qi * 16] = hn;
        if (t == T_ALL - 1) {
          out[HS_N + (size_t)(b_base + row) * HD + c_col] = hn;                         // h_T
          out[HS_N + (size_t)NBATCH * HD + (size_t)(b_base + row) * HD + c_col] = cn;   // c_T
        }
      }
    }
#pragma unroll
    for (int r = 0; r < 4; ++r) po[r] += HD;
    xgp += 4 * NG * 16;
    __syncthreads();   // h writes visible before next step's reads
  }

  { // persist state for next chunk
    const int idx = tid * 8, r = idx >> 8, c = idx & 255;
    *(h8*)(ws_h + (size_t)(b_base + r) * HD + c) = *(const h8*)(h_lds + r * 264 + c);
#pragma unroll
    for (int qi = 0; qi < 2; ++qi)
#pragma unroll
      for (int r2 = 0; r2 < 4; ++r2)
        ws_c[(size_t)(b_base + quad * 4 + r2) * HD + (2 * w + qi) * 16 + n] = creg[qi * 4 + r2];
  }
}

extern "C" void kernel_launch(void* const* d_in, const int* in_sizes, int n_in,
                              void* d_out, int out_size, void* d_ws, size_t ws_size,
                              hipStream_t stream) {
  (void)in_sizes; (void)n_in; (void)out_size;
  const float* x    = (const float*)d_in[0];
  const float* Wi   = (const float*)d_in[1];
  const float* Wh   = (const float*)d_in[2];
  const float* bias = (const float*)d_in[3];
  float* out = (float*)d_out;

  const size_t state_bytes = (size_t)NBATCH * HD * 2 + (size_t)NBATCH * HD * 4;
  int CT = T_ALL;
  while (CT > 32 && (size_t)CT * NG * 64 * 2 + state_bytes > ws_size) CT >>= 1;

  _Float16* xg   = (_Float16*)d_ws;
  _Float16* ws_h = (_Float16*)((char*)d_ws + (size_t)CT * NG * 64 * 2);
  float*    ws_c = (float*)((char*)ws_h + (size_t)NBATCH * HD * 2);

  (void)hipFuncSetAttribute((const void*)lstm_recur,
                            hipFuncAttributeMaxDynamicSharedMemorySize, SMEM_TOTAL);

  for (int t0 = 0; t0 < T_ALL; t0 += CT) {
    lstm_proj<<<dim3(CT), dim3(256), 0, stream>>>(x, Wi, bias, xg, t0);
    lstm_recur<<<dim3(4), dim3(512), SMEM_TOTAL, stream>>>(xg, Wh, out, ws_h, ws_c, t0, CT);
  }
}